// Round 16
// baseline (94.240 us; speedup 1.0000x reference)
//
#include <hip/hip_runtime.h>
#include <hip/hip_bf16.h>

// Problem constants
#define NTOK 2048
#define TOPK 2
#define HS   512
#define FFN  2048
#define NE   8
#define TASSIGN (NTOK*TOPK)   // 4096
#define PAD  5120             // 4096 + 8*128
#define MAXT128 40
#define MAXT64  72

typedef __attribute__((ext_vector_type(8))) short bf16x8;
typedef __attribute__((ext_vector_type(8))) unsigned short u16x8;
typedef __attribute__((ext_vector_type(4))) float f32x4;

// ws layout (byte offsets); total ~67.15 MB
static const size_t OFF_XBF  = 0;            // [NTOK*HS] bf16
static const size_t OFF_W1T  = 2097152;      // [E][FFN][HS] bf16
static const size_t OFF_W2T  = 18874368;     // [E][HS][FFN] bf16
static const size_t OFF_H    = 35651584;     // [PAD][FFN] bf16
static const size_t OFF_OUTV = 56623104;     // [2][PAD][HS] bf16 (split-K partials)
static const size_t OFF_RT   = 67108864;     // rowtok [PAD] int
static const size_t OFF_HROF = 67129344;     // hrof [TASSIGN] int
static const size_t OFF_TE128= 67145728;
static const size_t OFF_TR128= 67145888;
static const size_t OFF_TE64 = 67146048;
static const size_t OFF_TR64 = 67146336;

__device__ __forceinline__ unsigned short f2bf(float f) {
    union { __hip_bfloat16 h; unsigned short u; } v;
    v.h = __float2bfloat16(f);
    return v.u;
}

__device__ __forceinline__ float bf2f(unsigned short u) {
    union { unsigned int i; float f; } v;
    v.i = ((unsigned int)u) << 16;
    return v.f;
}

__device__ __forceinline__ int swz(int r, int byte_off) {
    return byte_off ^ ((r & 7) << 4);
}

// tanh-approx GELU = x*sigmoid(x*(1.59577 + 0.0713548*x^2)); |err| < 5e-4.
__device__ __forceinline__ float gelu_fast(float x) {
    float z2 = x * fmaf(0.0713548162726f, x * x, 1.5957691216057f);
    float e = __expf(z2);
    return x - __fdividef(x, e + 1.0f);
}

#define GLOAD16(gsrc, ldst) \
    __builtin_amdgcn_global_load_lds((const __attribute__((address_space(1))) void*)(gsrc), \
                                     (__attribute__((address_space(3))) void*)(ldst), 16, 0, 0)

// ---- wide transpose (R12-proven): 32(row)x64(col) f32 tile -> bf16 [col][row],
//      16B/lane reads AND writes; caller provides 32*72-ushort LDS scratch ----
__device__ __forceinline__ void dev_tr2(const float* __restrict__ in,
                                        unsigned short* __restrict__ out,
                                        int R, int C, int e, int rb, int cb,
                                        int tid, unsigned short* t) {
    const float* ip = in + (size_t)e * R * C + (size_t)rb * C + cb;
    unsigned short* op = out + (size_t)e * C * R + (size_t)cb * R + rb;
    int r = tid >> 3, c8 = (tid & 7) * 8;
    float4 v0 = *(const float4*)(ip + (size_t)r * C + c8);
    float4 v1 = *(const float4*)(ip + (size_t)r * C + c8 + 4);
    ushort4 lo, hi;
    lo.x = f2bf(v0.x); lo.y = f2bf(v0.y); lo.z = f2bf(v0.z); lo.w = f2bf(v0.w);
    hi.x = f2bf(v1.x); hi.y = f2bf(v1.y); hi.z = f2bf(v1.z); hi.w = f2bf(v1.w);
    *(ushort4*)(t + r * 72 + c8)     = lo;
    *(ushort4*)(t + r * 72 + c8 + 4) = hi;
    __syncthreads();
    int c = tid >> 2, r8 = (tid & 3) * 8;
    ushort4 a, b;
    a.x = t[(r8 + 0) * 72 + c]; a.y = t[(r8 + 1) * 72 + c];
    a.z = t[(r8 + 2) * 72 + c]; a.w = t[(r8 + 3) * 72 + c];
    b.x = t[(r8 + 4) * 72 + c]; b.y = t[(r8 + 5) * 72 + c];
    b.z = t[(r8 + 6) * 72 + c]; b.w = t[(r8 + 7) * 72 + c];
    *(ushort4*)(op + (size_t)c * R + r8)     = a;
    *(ushort4*)(op + (size_t)c * R + r8 + 4) = b;
}

// ---- prep: setup (1) + x->bf16 (512) + w1T wide tiles (4096).  w2T -> GEMM1. ----
__global__ __launch_bounds__(256) void k_prep(
        const float* __restrict__ x, const float* __restrict__ w1,
        const int* __restrict__ ei,
        unsigned short* __restrict__ xbf, unsigned short* __restrict__ w1T,
        int* __restrict__ rowtok, int* __restrict__ hrof,
        int* __restrict__ te128, int* __restrict__ tr128,
        int* __restrict__ te64, int* __restrict__ tr64) {
    __shared__ unsigned short tsh[32 * 72];
    int b = blockIdx.x;
    int tid = threadIdx.x;
    if (b == 0) {
        __shared__ int cnt[NE], offpad[NE], cur[NE];
        for (int i = tid; i < PAD; i += 256) rowtok[i] = 0;
        if (tid < NE) cnt[tid] = 0;
        __syncthreads();
        for (int a = tid; a < TASSIGN; a += 256) atomicAdd(&cnt[ei[a]], 1);
        __syncthreads();
        if (tid == 0) {
            int o = 0, t1 = 0, t2 = 0;
            for (int e = 0; e < NE; e++) {
                offpad[e] = o; cur[e] = 0;
                for (int r = 0; r < cnt[e]; r += 128) { te128[t1] = e; tr128[t1] = o + r; t1++; }
                for (int r = 0; r < cnt[e]; r += 64)  { te64[t2]  = e; tr64[t2]  = o + r; t2++; }
                o += (cnt[e] + 127) / 128 * 128;
            }
            for (; t1 < MAXT128; t1++) te128[t1] = -1;
            for (; t2 < MAXT64;  t2++) te64[t2]  = -1;
        }
        __syncthreads();
        for (int a = tid; a < TASSIGN; a += 256) {
            int e = ei[a];
            int r = atomicAdd(&cur[e], 1);
            int hr = offpad[e] + r;
            rowtok[hr] = a >> 1;       // token = assignment / TOPK
            hrof[a] = hr;
        }
    } else if (b < 1 + 512) {
        int i = ((b - 1) * 256 + tid) * 8;
        float4 v0 = *(const float4*)(x + i);
        float4 v1 = *(const float4*)(x + i + 4);
        u16x8 o;
        o[0] = f2bf(v0.x); o[1] = f2bf(v0.y); o[2] = f2bf(v0.z); o[3] = f2bf(v0.w);
        o[4] = f2bf(v1.x); o[5] = f2bf(v1.y); o[6] = f2bf(v1.z); o[7] = f2bf(v1.w);
        *(u16x8*)(xbf + i) = o;
    } else {
        // w1 [E][HS=512][FFN=2048] -> w1T [E][FFN][HS]; 4096 tiles of 32x64
        int blk = b - 513;
        int e = blk >> 9, rem = blk & 511;
        dev_tr2(w1, w1T, HS, FFN, e, (rem >> 5) * 32, (rem & 31) * 64, tid, tsh);
    }
}

// ---- GEMM1 + interleaved w2 transpose.  Grid 1536 blocks:
//      b%6==0  -> one of 256 transpose blocks (16 wide 32x64 tiles each, ~BW-bound,
//                 spread across CUs so each CU holds ~2 gemm + ~1 transpose block;
//                 streams w2's 80MB in GEMM1's HBM headroom, retires early)
//      else    -> one of 1280 R9-pipeline gemm blocks (128x64 tile, K=512)
__global__ __launch_bounds__(256) void k_g1w2t(
        const unsigned short* __restrict__ A,   // xbf
        const unsigned short* __restrict__ B,   // w1T
        unsigned short* __restrict__ Hout,
        const int* __restrict__ rowtok,
        const int* __restrict__ te, const int* __restrict__ tr,
        const float* __restrict__ w2, unsigned short* __restrict__ w2T) {
    constexpr int BM = 128, BN = 64, K = HS, N = FFN;
    constexpr int MI = 4, NJ = 2, PA = 4, PB = 2;
    constexpr int ABYTES = BM * 64 * 2, BBYTES = BN * 64 * 2;  // 16KB, 8KB
    constexpr int NSTEP = K / 64;                               // 8

    __shared__ int4 ldsv[(2 * (ABYTES + BBYTES)) / 16];         // 48KB shared
    int b = blockIdx.x;
    int tid = threadIdx.x;

    if (b % 6 == 0) {
        // ---- w2 [E][FFN][HS] -> w2T [E][HS][FFN]; 4096 tiles, 16 per block ----
        unsigned short* tsh = (unsigned short*)ldsv;
        int tb = b / 6;                          // 0..255
#pragma unroll 1
        for (int i = 0; i < 16; ++i) {
            if (i) __syncthreads();              // prev iteration's LDS reads done
            int t = tb * 16 + i;
            int e2 = t >> 9;                     // 512 tiles per expert
            int rem = t & 511;                   // 64 row-tiles x 8 col-tiles
            dev_tr2(w2, w2T, FFN, HS, e2, (rem >> 3) * 32, (rem & 7) * 64, tid, tsh);
        }
        return;
    }

    // ---- GEMM1 path (R9-proven 2-buffer counted-vmcnt pipeline) ----
    int bb = b - 1 - b / 6;                      // 0..1279
    int ct = bb & 31;                            // 32 col tiles
    int mt = bb >> 5;                            // 40 m tiles
    int e = te[mt];
    if (e < 0) return;
    int hr0 = tr[mt];

    char* A0 = (char*)ldsv;
    char* A1 = A0 + ABYTES;
    char* B0 = A1 + ABYTES;
    char* B1 = B0 + BBYTES;

    int lane = tid & 63, wave = tid >> 6;
    int wm = wave >> 1, wn = wave & 1;

    const char* asrc[PA];
    const char* bsrc[PB];
    int adoff[PA], bdoff[PB];
#pragma unroll
    for (int p = 0; p < PA; p++) {
        int idx = p * 256 + tid;
        int r = idx >> 3, c8 = idx & 7;
        int c8s = c8 ^ (r & 7);
        size_t row = (size_t)rowtok[hr0 + r];
        asrc[p] = (const char*)(A + row * K) + c8s * 16;
        adoff[p] = (p * 256 + wave * 64) * 16;
    }
#pragma unroll
    for (int p = 0; p < PB; p++) {
        int idx = p * 256 + tid;
        int r = idx >> 3, c8 = idx & 7;
        int c8s = c8 ^ (r & 7);
        bsrc[p] = (const char*)(B + ((size_t)e * N + (size_t)ct * BN + r) * K) + c8s * 16;
        bdoff[p] = (p * 256 + wave * 64) * 16;
    }

    f32x4 acc[MI][NJ] = {};

    auto stage = [&](char* Ad, char* Bd, int s) {
        int kb = s * 128;
#pragma unroll
        for (int p = 0; p < PA; p++) GLOAD16(asrc[p] + kb, Ad + adoff[p]);
#pragma unroll
        for (int p = 0; p < PB; p++) GLOAD16(bsrc[p] + kb, Bd + bdoff[p]);
    };
    auto compute = [&](const char* As, const char* Bs) {
#pragma unroll
        for (int kk = 0; kk < 64; kk += 32) {
            bf16x8 af[MI], bfv[NJ];
#pragma unroll
            for (int i = 0; i < MI; i++) {
                int ar = wm * (BM / 2) + i * 16 + (lane & 15);
                af[i] = *(const bf16x8*)(As + swz(ar, ar * 128 + kk * 2 + (lane >> 4) * 16));
            }
#pragma unroll
            for (int j = 0; j < NJ; j++) {
                int bc = wn * (BN / 2) + j * 16 + (lane & 15);
                bfv[j] = *(const bf16x8*)(Bs + swz(bc, bc * 128 + kk * 2 + (lane >> 4) * 16));
            }
#pragma unroll
            for (int i = 0; i < MI; i++)
#pragma unroll
                for (int j = 0; j < NJ; j++)
                    acc[i][j] = __builtin_amdgcn_mfma_f32_16x16x32_bf16(af[i], bfv[j], acc[i][j], 0, 0, 0);
        }
    };
    auto waitv_lps = [&]() { asm volatile("s_waitcnt vmcnt(6)" ::: "memory"); };
    auto waitv0 = [&]() { asm volatile("s_waitcnt vmcnt(0)" ::: "memory"); };
    auto waitlgkm = [&]() { asm volatile("s_waitcnt lgkmcnt(0)" ::: "memory"); };
    auto bar = [&]() {
        __builtin_amdgcn_sched_barrier(0);
        __builtin_amdgcn_s_barrier();
        __builtin_amdgcn_sched_barrier(0);
        asm volatile("" ::: "memory");
    };

    stage(A0, B0, 0);
    stage(A1, B1, 1);
#pragma unroll 1
    for (int s = 0; s + 2 < NSTEP; s += 2) {
        waitv_lps(); bar();
        compute(A0, B0);
        waitlgkm(); bar();
        stage(A0, B0, s + 2);
        waitv_lps(); bar();
        compute(A1, B1);
        waitlgkm(); bar();
        if (s + 3 < NSTEP) stage(A1, B1, s + 3);
    }
    waitv_lps(); bar();
    compute(A0, B0);
    waitv0(); bar();
    compute(A1, B1);

    // epilogue: fast gelu, bf16 store
#pragma unroll
    for (int i = 0; i < MI; i++)
#pragma unroll
        for (int j = 0; j < NJ; j++)
#pragma unroll
            for (int q = 0; q < 4; q++) {
                int row = hr0 + wm * (BM / 2) + i * 16 + (lane >> 4) * 4 + q;
                int col = ct * BN + wn * (BN / 2) + j * 16 + (lane & 15);
                Hout[(size_t)row * N + col] = f2bf(gelu_fast(acc[i][j][q]));
            }
}

// ---- GEMM2: R9-proven 2-buffer pipeline, split-K=2, bf16 partial outputs ----
template<int BM, int BN, int KFULL, int KLOC>
__global__ __launch_bounds__(256) void k_gemm2(
        const unsigned short* __restrict__ A,
        const unsigned short* __restrict__ B,
        unsigned short* __restrict__ outp,
        const int* __restrict__ te, const int* __restrict__ tr, int N) {
    constexpr int MI = BM / 32, NJ = BN / 32;
    constexpr int PA = BM / 32, PB = BN / 32;
    constexpr int ABYTES = BM * 64 * 2, BBYTES = BN * 64 * 2;
    constexpr int NSTEP = KLOC / 64;
    static_assert(NSTEP % 2 == 0 && NSTEP >= 4, "even steps >= 4");

    int mt = blockIdx.y;
    int e = te[mt];
    if (e < 0) return;
    int hr0 = tr[mt];
    int ct = blockIdx.x;
    int kz = blockIdx.z;
    int k0 = kz * KLOC;

    __shared__ int4 ldsv[(2 * (ABYTES + BBYTES)) / 16];
    char* A0 = (char*)ldsv;
    char* A1 = A0 + ABYTES;
    char* B0 = A1 + ABYTES;
    char* B1 = B0 + BBYTES;

    int tid = threadIdx.x;
    int lane = tid & 63, wave = tid >> 6;
    int wm = wave >> 1, wn = wave & 1;

    const char* asrc[PA];
    const char* bsrc[PB];
    int adoff[PA], bdoff[PB];
#pragma unroll
    for (int p = 0; p < PA; p++) {
        int idx = p * 256 + tid;
        int r = idx >> 3, c8 = idx & 7;
        int c8s = c8 ^ (r & 7);
        asrc[p] = (const char*)(A + (size_t)(hr0 + r) * KFULL + k0) + c8s * 16;
        adoff[p] = (p * 256 + wave * 64) * 16;
    }
#pragma unroll
    for (int p = 0; p < PB; p++) {
        int idx = p * 256 + tid;
        int r = idx >> 3, c8 = idx & 7;
        int c8s = c8 ^ (r & 7);
        bsrc[p] = (const char*)(B + ((size_t)e * N + (size_t)ct * BN + r) * KFULL + k0) + c8s * 16;
        bdoff[p] = (p * 256 + wave * 64) * 16;
    }

    f32x4 acc[MI][NJ] = {};

    auto stage = [&](char* Ad, char* Bd, int s) {
        int kb = s * 128;
#pragma unroll
        for (int p = 0; p < PA; p++) GLOAD16(asrc[p] + kb, Ad + adoff[p]);
#pragma unroll
        for (int p = 0; p < PB; p++) GLOAD16(bsrc[p] + kb, Bd + bdoff[p]);
    };
    auto compute = [&](const char* As, const char* Bs) {
#pragma unroll
        for (int kk = 0; kk < 64; kk += 32) {
            bf16x8 af[MI], bfv[NJ];
#pragma unroll
            for (int i = 0; i < MI; i++) {
                int ar = wm * (BM / 2) + i * 16 + (lane & 15);
                af[i] = *(const bf16x8*)(As + swz(ar, ar * 128 + kk * 2 + (lane >> 4) * 16));
            }
#pragma unroll
            for (int j = 0; j < NJ; j++) {
                int bc = wn * (BN / 2) + j * 16 + (lane & 15);
                bfv[j] = *(const bf16x8*)(Bs + swz(bc, bc * 128 + kk * 2 + (lane >> 4) * 16));
            }
#pragma unroll
            for (int i = 0; i < MI; i++)
#pragma unroll
                for (int j = 0; j < NJ; j++)
                    acc[i][j] = __builtin_amdgcn_mfma_f32_16x16x32_bf16(af[i], bfv[j], acc[i][j], 0, 0, 0);
        }
    };
    auto waitv_lps = [&]() {
        if constexpr (PA + PB == 6)      { asm volatile("s_waitcnt vmcnt(6)" ::: "memory"); }
        else if constexpr (PA + PB == 4) { asm volatile("s_waitcnt vmcnt(4)" ::: "memory"); }
        else                             { asm volatile("s_waitcnt vmcnt(0)" ::: "memory"); }
    };
    auto waitv0 = [&]() { asm volatile("s_waitcnt vmcnt(0)" ::: "memory"); };
    auto waitlgkm = [&]() { asm volatile("s_waitcnt lgkmcnt(0)" ::: "memory"); };
    auto bar = [&]() {
        __builtin_amdgcn_sched_barrier(0);
        __builtin_amdgcn_s_barrier();
        __builtin_amdgcn_sched_barrier(0);
        asm volatile("" ::: "memory");
    };

    stage(A0, B0, 0);
    stage(A1, B1, 1);
#pragma unroll 1
    for (int s = 0; s + 2 < NSTEP; s += 2) {
        waitv_lps(); bar();
        compute(A0, B0);
        waitlgkm(); bar();
        stage(A0, B0, s + 2);
        waitv_lps(); bar();
        compute(A1, B1);
        waitlgkm(); bar();
        if (s + 3 < NSTEP) stage(A1, B1, s + 3);
    }
    waitv_lps(); bar();
    compute(A0, B0);
    waitv0(); bar();
    compute(A1, B1);

    unsigned short* O = outp + (size_t)kz * PAD * HS;
#pragma unroll
    for (int i = 0; i < MI; i++)
#pragma unroll
        for (int j = 0; j < NJ; j++)
#pragma unroll
            for (int q = 0; q < 4; q++) {
                int row = hr0 + wm * (BM / 2) + i * 16 + (lane >> 4) * 4 + q;
                int col = ct * BN + wn * (BN / 2) + j * 16 + (lane & 15);
                O[(size_t)row * N + col] = f2bf(acc[i][j][q]);
            }
}

// ---- combine: sum bf16 split-K partials; y[t] = w0*o0 + w1*o1 ;
//      buffer[t][0..7] fully written (zeros incl.) -> no memset anywhere. ----
__global__ __launch_bounds__(256) void k_combine(
        const unsigned short* __restrict__ outv, const int* __restrict__ ei,
        const float* __restrict__ ew, const int* __restrict__ hrof,
        float* __restrict__ y, float* __restrict__ buf) {
    constexpr size_t SPLIT = (size_t)PAD * HS;   // elements between partials
    int g = blockIdx.x * 256 + threadIdx.x;      // over NTOK*HS/8
    int t = g >> 6, c8 = g & 63;                 // HS/8 = 64 chunks/token
    int a0 = 2 * t, a1 = a0 + 1;
    int h0 = hrof[a0], h1 = hrof[a1];
    u16x8 q0a = *(const u16x8*)(outv + (size_t)h0 * HS + c8 * 8);
    u16x8 q0b = *(const u16x8*)(outv + SPLIT + (size_t)h0 * HS + c8 * 8);
    u16x8 q1a = *(const u16x8*)(outv + (size_t)h1 * HS + c8 * 8);
    u16x8 q1b = *(const u16x8*)(outv + SPLIT + (size_t)h1 * HS + c8 * 8);
    float w0 = ew[a0], w1 = ew[a1];
    float o0[8], o1[8], yy[8];
#pragma unroll
    for (int k = 0; k < 8; k++) {
        o0[k] = bf2f(q0a[k]) + bf2f(q0b[k]);
        o1[k] = bf2f(q1a[k]) + bf2f(q1b[k]);
        yy[k] = w0 * o0[k] + w1 * o1[k];
    }
    float* yp = y + (size_t)t * HS + c8 * 8;
    *(float4*)(yp)     = make_float4(yy[0], yy[1], yy[2], yy[3]);
    *(float4*)(yp + 4) = make_float4(yy[4], yy[5], yy[6], yy[7]);
    int e0 = ei[a0], e1 = ei[a1];
    float* bt = buf + (size_t)t * (NE * HS) + c8 * 8;
#pragma unroll
    for (int e = 0; e < NE; e++) {
        float v[8];
#pragma unroll
        for (int k = 0; k < 8; k++)
            v[k] = (e == e0 ? o0[k] : 0.0f) + (e == e1 ? o1[k] : 0.0f);
        float* be = bt + (size_t)e * HS;
        *(float4*)(be)     = make_float4(v[0], v[1], v[2], v[3]);
        *(float4*)(be + 4) = make_float4(v[4], v[5], v[6], v[7]);
    }
}

extern "C" void kernel_launch(void* const* d_in, const int* in_sizes, int n_in,
                              void* d_out, int out_size, void* d_ws, size_t ws_size,
                              hipStream_t stream) {
    const float* x  = (const float*)d_in[0];
    const float* ew = (const float*)d_in[1];
    const int*   ei = (const int*)d_in[2];
    const float* w1 = (const float*)d_in[3];
    const float* w2 = (const float*)d_in[4];

    char* ws = (char*)d_ws;
    unsigned short* xbf  = (unsigned short*)(ws + OFF_XBF);
    unsigned short* w1T  = (unsigned short*)(ws + OFF_W1T);
    unsigned short* w2T  = (unsigned short*)(ws + OFF_W2T);
    unsigned short* Hb   = (unsigned short*)(ws + OFF_H);
    unsigned short* outv = (unsigned short*)(ws + OFF_OUTV);
    int*            rowtok = (int*)(ws + OFF_RT);
    int*            hrof   = (int*)(ws + OFF_HROF);
    int*            te128  = (int*)(ws + OFF_TE128);
    int*            tr128  = (int*)(ws + OFF_TR128);
    int*            te64   = (int*)(ws + OFF_TE64);
    int*            tr64   = (int*)(ws + OFF_TR64);

    float* y   = (float*)d_out;
    float* buf = (float*)d_out + (size_t)NTOK * HS;

    // prep: setup + x->bf16 + w1T (wide).  w2T folded into the GEMM1 launch.
    k_prep<<<1 + 512 + 4096, 256, 0, stream>>>(
        x, w1, ei, xbf, w1T, rowtok, hrof, te128, tr128, te64, tr64);
    // GEMM1 (1280 blocks) + interleaved wide w2-transpose (256 blocks at b%6==0)
    k_g1w2t<<<1536, 256, 0, stream>>>(
        xbf, w1T, Hb, rowtok, te128, tr128, w2, w2T);
    // GEMM2 -> bf16 partials: 64x64 tiles, split-K=2, 1152 blocks
    k_gemm2<64, 64, FFN, FFN / 2><<<dim3(HS / 64, MAXT64, 2), 256, 0, stream>>>(
        Hb, w2T, outv, te64, tr64, HS);
    // combine split-K partials into y and buffer (writes ALL buffer slots)
    k_combine<<<NTOK * HS / 8 / 256, 256, 0, stream>>>(
        outv, ei, ew, hrof, y, buf);
}

// Round 17
// 84.012 us; speedup vs baseline: 1.1217x; 1.1217x over previous
//
#include <hip/hip_runtime.h>
#include <hip/hip_bf16.h>

// Problem constants
#define NTOK 2048
#define TOPK 2
#define HS   512
#define FFN  2048
#define NE   8
#define TASSIGN (NTOK*TOPK)   // 4096
#define PAD  5120             // 4096 + 8*128
#define MAXT128 40
#define MAXT64  72

typedef __attribute__((ext_vector_type(8))) short bf16x8;
typedef __attribute__((ext_vector_type(8))) unsigned short u16x8;
typedef __attribute__((ext_vector_type(4))) float f32x4;

// ws layout (byte offsets); total ~67.15 MB
static const size_t OFF_XBF  = 0;            // [NTOK*HS] bf16
static const size_t OFF_W1T  = 2097152;      // [E][FFN][HS] bf16
static const size_t OFF_W2T  = 18874368;     // [E][HS][FFN] bf16
static const size_t OFF_H    = 35651584;     // [PAD][FFN] bf16
static const size_t OFF_OUTV = 56623104;     // [2][PAD][HS] bf16 (split-K partials)
static const size_t OFF_RT   = 67108864;     // rowtok [PAD] int
static const size_t OFF_HROF = 67129344;     // hrof [TASSIGN] int
static const size_t OFF_TE128= 67145728;
static const size_t OFF_TR128= 67145888;
static const size_t OFF_TE64 = 67146048;
static const size_t OFF_TR64 = 67146336;

__device__ __forceinline__ unsigned short f2bf(float f) {
    union { __hip_bfloat16 h; unsigned short u; } v;
    v.h = __float2bfloat16(f);
    return v.u;
}

__device__ __forceinline__ float bf2f(unsigned short u) {
    union { unsigned int i; float f; } v;
    v.i = ((unsigned int)u) << 16;
    return v.f;
}

__device__ __forceinline__ int swz(int r, int byte_off) {
    return byte_off ^ ((r & 7) << 4);
}

// tanh-approx GELU = x*sigmoid(x*(1.59577 + 0.0713548*x^2)); |err| < 5e-4.
__device__ __forceinline__ float gelu_fast(float x) {
    float z2 = x * fmaf(0.0713548162726f, x * x, 1.5957691216057f);
    float e = __expf(z2);
    return x - __fdividef(x, e + 1.0f);
}

#define GLOAD16(gsrc, ldst) \
    __builtin_amdgcn_global_load_lds((const __attribute__((address_space(1))) void*)(gsrc), \
                                     (__attribute__((address_space(3))) void*)(ldst), 16, 0, 0)

// ---- fused prep: setup (block 0) + x->bf16 (1024) + w1T (8192) + w2T (8192) ----
__device__ __forceinline__ void dev_transpose(const float* __restrict__ in,
                                              unsigned short* __restrict__ out,
                                              int R, int C, int e, int rb, int cb, int tid) {
    __shared__ unsigned short t[32][33];
    int tx = tid & 31, ty = tid >> 5;          // 32 x 8
    const float* ip = in + (size_t)e * R * C;
    unsigned short* op = out + (size_t)e * C * R;
#pragma unroll
    for (int i = 0; i < 4; i++) {
        int r = ty + i * 8;
        t[r][tx] = f2bf(ip[(size_t)(rb + r) * C + cb + tx]);
    }
    __syncthreads();
#pragma unroll
    for (int i = 0; i < 4; i++) {
        int c = ty + i * 8;
        op[(size_t)(cb + c) * R + rb + tx] = t[tx][c];
    }
}

__global__ __launch_bounds__(256) void k_prep(
        const float* __restrict__ x, const float* __restrict__ w1,
        const float* __restrict__ w2, const int* __restrict__ ei,
        unsigned short* __restrict__ xbf, unsigned short* __restrict__ w1T,
        unsigned short* __restrict__ w2T,
        int* __restrict__ rowtok, int* __restrict__ hrof,
        int* __restrict__ te128, int* __restrict__ tr128,
        int* __restrict__ te64, int* __restrict__ tr64) {
    int b = blockIdx.x;
    int tid = threadIdx.x;
    if (b == 0) {
        __shared__ int cnt[NE], offpad[NE], cur[NE];
        for (int i = tid; i < PAD; i += 256) rowtok[i] = 0;
        if (tid < NE) cnt[tid] = 0;
        __syncthreads();
        for (int a = tid; a < TASSIGN; a += 256) atomicAdd(&cnt[ei[a]], 1);
        __syncthreads();
        if (tid == 0) {
            int o = 0, t1 = 0, t2 = 0;
            for (int e = 0; e < NE; e++) {
                offpad[e] = o; cur[e] = 0;
                for (int r = 0; r < cnt[e]; r += 128) { te128[t1] = e; tr128[t1] = o + r; t1++; }
                for (int r = 0; r < cnt[e]; r += 64)  { te64[t2]  = e; tr64[t2]  = o + r; t2++; }
                o += (cnt[e] + 127) / 128 * 128;
            }
            for (; t1 < MAXT128; t1++) te128[t1] = -1;
            for (; t2 < MAXT64;  t2++) te64[t2]  = -1;
        }
        __syncthreads();
        for (int a = tid; a < TASSIGN; a += 256) {
            int e = ei[a];
            int r = atomicAdd(&cur[e], 1);
            int hr = offpad[e] + r;
            rowtok[hr] = a >> 1;       // token = assignment / TOPK
            hrof[a] = hr;
        }
    } else if (b < 1 + 1024) {
        int i = ((b - 1) * 256 + tid) * 4;
        float4 v = *(const float4*)(x + i);
        ushort4 o;
        o.x = f2bf(v.x); o.y = f2bf(v.y); o.z = f2bf(v.z); o.w = f2bf(v.w);
        *(ushort4*)(xbf + i) = o;
    } else if (b < 1 + 1024 + 8192) {
        int blk = b - 1025;
        int e = blk >> 10, rem = blk & 1023;
        dev_transpose(w1, w1T, HS, FFN, e, (rem >> 6) * 32, (rem & 63) * 32, tid);
    } else {
        int blk = b - 9217;
        int e = blk >> 10, rem = blk & 1023;
        dev_transpose(w2, w2T, FFN, HS, e, (rem >> 4) * 32, (rem & 15) * 32, tid);
    }
}

// ---- grouped GEMM: 2-buffer pipeline with COUNTED vmcnt across raw barriers ----
// Per step: [vmcnt(LPS); barrier]  -> buf[s] complete (next step's loads stay in flight)
//           ds_read + MFMA         -> consumes buf[s]
//           [lgkmcnt(0); barrier]  -> all waves done reading buf[s]
//           stage(s+2) into buf[s] -> overwrite now safe
// G1=true:  H = gelu_fast(A_gathered @ B^T-layout), bf16 out (kz unused)
// G1=false: bf16 split-K partials, blockIdx.z selects K-slice
template<int BM, int BN, int KFULL, int KLOC, bool G1>
__global__ __launch_bounds__(256) void k_gemm(
        const unsigned short* __restrict__ A,
        const unsigned short* __restrict__ B,
        unsigned short* __restrict__ outp,
        const int* __restrict__ rowtok,
        const int* __restrict__ te, const int* __restrict__ tr, int N) {
    constexpr int MI = BM / 32, NJ = BN / 32;
    constexpr int PA = BM / 32, PB = BN / 32;       // gload sets of 256 lanes x 16B
    constexpr int ABYTES = BM * 64 * 2, BBYTES = BN * 64 * 2;
    constexpr int NSTEP = KLOC / 64;
    static_assert(NSTEP % 2 == 0 && NSTEP >= 4, "even steps >= 4");

    int mt = blockIdx.y;
    int e = te[mt];
    if (e < 0) return;
    int hr0 = tr[mt];
    int ct = blockIdx.x;
    int kz = blockIdx.z;
    int k0 = kz * KLOC;

    __shared__ int4 ldsv[(2 * (ABYTES + BBYTES)) / 16];
    char* A0 = (char*)ldsv;
    char* A1 = A0 + ABYTES;
    char* B0 = A1 + ABYTES;
    char* B1 = B0 + BBYTES;

    int tid = threadIdx.x;
    int lane = tid & 63, wave = tid >> 6;
    int wm = wave >> 1, wn = wave & 1;

    // per-thread pre-swizzled global sources (chunk c8 of row r fetched from c8^(r&7))
    const char* asrc[PA];
    const char* bsrc[PB];
    int adoff[PA], bdoff[PB];
#pragma unroll
    for (int p = 0; p < PA; p++) {
        int idx = p * 256 + tid;
        int r = idx >> 3, c8 = idx & 7;
        int c8s = c8 ^ (r & 7);
        size_t row = G1 ? (size_t)rowtok[hr0 + r] : (size_t)(hr0 + r);
        asrc[p] = (const char*)(A + row * KFULL + k0) + c8s * 16;
        adoff[p] = (p * 256 + wave * 64) * 16;      // wave-uniform linear LDS dest
    }
#pragma unroll
    for (int p = 0; p < PB; p++) {
        int idx = p * 256 + tid;
        int r = idx >> 3, c8 = idx & 7;
        int c8s = c8 ^ (r & 7);
        bsrc[p] = (const char*)(B + ((size_t)e * N + (size_t)ct * BN + r) * KFULL + k0) + c8s * 16;
        bdoff[p] = (p * 256 + wave * 64) * 16;
    }

    f32x4 acc[MI][NJ] = {};

    auto stage = [&](char* Ad, char* Bd, int s) {
        int kb = s * 128;                            // 64 k-elems * 2B
#pragma unroll
        for (int p = 0; p < PA; p++) GLOAD16(asrc[p] + kb, Ad + adoff[p]);
#pragma unroll
        for (int p = 0; p < PB; p++) GLOAD16(bsrc[p] + kb, Bd + bdoff[p]);
    };
    auto compute = [&](const char* As, const char* Bs) {
#pragma unroll
        for (int kk = 0; kk < 64; kk += 32) {
            bf16x8 af[MI], bfv[NJ];
#pragma unroll
            for (int i = 0; i < MI; i++) {
                int ar = wm * (BM / 2) + i * 16 + (lane & 15);
                af[i] = *(const bf16x8*)(As + swz(ar, ar * 128 + kk * 2 + (lane >> 4) * 16));
            }
#pragma unroll
            for (int j = 0; j < NJ; j++) {
                int bc = wn * (BN / 2) + j * 16 + (lane & 15);
                bfv[j] = *(const bf16x8*)(Bs + swz(bc, bc * 128 + kk * 2 + (lane >> 4) * 16));
            }
#pragma unroll
            for (int i = 0; i < MI; i++)
#pragma unroll
                for (int j = 0; j < NJ; j++)
                    acc[i][j] = __builtin_amdgcn_mfma_f32_16x16x32_bf16(af[i], bfv[j], acc[i][j], 0, 0, 0);
        }
    };
    // counted vmcnt: wait until only the NEWEST stage (LPS loads) remains in flight
    auto waitv_lps = [&]() {
        if constexpr (PA + PB == 6)      { asm volatile("s_waitcnt vmcnt(6)" ::: "memory"); }
        else if constexpr (PA + PB == 4) { asm volatile("s_waitcnt vmcnt(4)" ::: "memory"); }
        else                             { asm volatile("s_waitcnt vmcnt(0)" ::: "memory"); }
    };
    auto waitv0 = [&]() { asm volatile("s_waitcnt vmcnt(0)" ::: "memory"); };
    auto waitlgkm = [&]() { asm volatile("s_waitcnt lgkmcnt(0)" ::: "memory"); };
    auto bar = [&]() {
        __builtin_amdgcn_sched_barrier(0);
        __builtin_amdgcn_s_barrier();
        __builtin_amdgcn_sched_barrier(0);
        asm volatile("" ::: "memory");
    };

    // prologue: two stages in flight
    stage(A0, B0, 0);
    stage(A1, B1, 1);
#pragma unroll 1
    for (int s = 0; s + 2 < NSTEP; s += 2) {
        waitv_lps(); bar();                 // buf0(step s) ready; step s+1 still in flight
        compute(A0, B0);
        waitlgkm(); bar();                  // all waves done reading buf0
        stage(A0, B0, s + 2);
        waitv_lps(); bar();                 // buf1(step s+1) ready
        compute(A1, B1);
        waitlgkm(); bar();
        if (s + 3 < NSTEP) stage(A1, B1, s + 3);
    }
    // tail: steps NSTEP-2 (buf0) and NSTEP-1 (buf1), no more staging
    waitv_lps(); bar();
    compute(A0, B0);
    waitv0(); bar();
    compute(A1, B1);

    if constexpr (G1) {
#pragma unroll
        for (int i = 0; i < MI; i++)
#pragma unroll
            for (int j = 0; j < NJ; j++)
#pragma unroll
                for (int q = 0; q < 4; q++) {
                    int row = hr0 + wm * (BM / 2) + i * 16 + (lane >> 4) * 4 + q;
                    int col = ct * BN + wn * (BN / 2) + j * 16 + (lane & 15);
                    outp[(size_t)row * N + col] = f2bf(gelu_fast(acc[i][j][q]));
                }
    } else {
        unsigned short* O = outp + (size_t)kz * PAD * HS;
#pragma unroll
        for (int i = 0; i < MI; i++)
#pragma unroll
            for (int j = 0; j < NJ; j++)
#pragma unroll
                for (int q = 0; q < 4; q++) {
                    int row = hr0 + wm * (BM / 2) + i * 16 + (lane >> 4) * 4 + q;
                    int col = ct * BN + wn * (BN / 2) + j * 16 + (lane & 15);
                    O[(size_t)row * N + col] = f2bf(acc[i][j][q]);
                }
    }
}

// ---- combine: sum bf16 split-K partials; y[t] = w0*o0 + w1*o1 ;
//      buffer[t][0..7] fully written (zeros incl.) -> no memset anywhere. ----
__global__ __launch_bounds__(256) void k_combine(
        const unsigned short* __restrict__ outv, const int* __restrict__ ei,
        const float* __restrict__ ew, const int* __restrict__ hrof,
        float* __restrict__ y, float* __restrict__ buf) {
    constexpr size_t SPLIT = (size_t)PAD * HS;   // elements between partials
    int g = blockIdx.x * 256 + threadIdx.x;      // over NTOK*HS/8
    int t = g >> 6, c8 = g & 63;                 // HS/8 = 64 chunks/token
    int a0 = 2 * t, a1 = a0 + 1;
    int h0 = hrof[a0], h1 = hrof[a1];
    u16x8 q0a = *(const u16x8*)(outv + (size_t)h0 * HS + c8 * 8);
    u16x8 q0b = *(const u16x8*)(outv + SPLIT + (size_t)h0 * HS + c8 * 8);
    u16x8 q1a = *(const u16x8*)(outv + (size_t)h1 * HS + c8 * 8);
    u16x8 q1b = *(const u16x8*)(outv + SPLIT + (size_t)h1 * HS + c8 * 8);
    float w0 = ew[a0], w1 = ew[a1];
    float o0[8], o1[8], yy[8];
#pragma unroll
    for (int k = 0; k < 8; k++) {
        o0[k] = bf2f(q0a[k]) + bf2f(q0b[k]);
        o1[k] = bf2f(q1a[k]) + bf2f(q1b[k]);
        yy[k] = w0 * o0[k] + w1 * o1[k];
    }
    float* yp = y + (size_t)t * HS + c8 * 8;
    *(float4*)(yp)     = make_float4(yy[0], yy[1], yy[2], yy[3]);
    *(float4*)(yp + 4) = make_float4(yy[4], yy[5], yy[6], yy[7]);
    int e0 = ei[a0], e1 = ei[a1];
    float* bt = buf + (size_t)t * (NE * HS) + c8 * 8;
#pragma unroll
    for (int e = 0; e < NE; e++) {
        float v[8];
#pragma unroll
        for (int k = 0; k < 8; k++)
            v[k] = (e == e0 ? o0[k] : 0.0f) + (e == e1 ? o1[k] : 0.0f);
        float* be = bt + (size_t)e * HS;
        *(float4*)(be)     = make_float4(v[0], v[1], v[2], v[3]);
        *(float4*)(be + 4) = make_float4(v[4], v[5], v[6], v[7]);
    }
}

extern "C" void kernel_launch(void* const* d_in, const int* in_sizes, int n_in,
                              void* d_out, int out_size, void* d_ws, size_t ws_size,
                              hipStream_t stream) {
    const float* x  = (const float*)d_in[0];
    const float* ew = (const float*)d_in[1];
    const int*   ei = (const int*)d_in[2];
    const float* w1 = (const float*)d_in[3];
    const float* w2 = (const float*)d_in[4];

    char* ws = (char*)d_ws;
    unsigned short* xbf  = (unsigned short*)(ws + OFF_XBF);
    unsigned short* w1T  = (unsigned short*)(ws + OFF_W1T);
    unsigned short* w2T  = (unsigned short*)(ws + OFF_W2T);
    unsigned short* Hb   = (unsigned short*)(ws + OFF_H);
    unsigned short* outv = (unsigned short*)(ws + OFF_OUTV);
    int*            rowtok = (int*)(ws + OFF_RT);
    int*            hrof   = (int*)(ws + OFF_HROF);
    int*            te128  = (int*)(ws + OFF_TE128);
    int*            tr128  = (int*)(ws + OFF_TR128);
    int*            te64   = (int*)(ws + OFF_TE64);
    int*            tr64   = (int*)(ws + OFF_TR64);

    float* y   = (float*)d_out;
    float* buf = (float*)d_out + (size_t)NTOK * HS;

    // fused prep: setup + xcvt + both weight transposes, one launch
    k_prep<<<1 + 1024 + 8192 + 8192, 256, 0, stream>>>(
        x, w1, w2, ei, xbf, w1T, w2T, rowtok, hrof, te128, tr128, te64, tr64);
    // GEMM1 + fast gelu -> H (bf16): 128x64 tiles, grid 32 x 40 = 1280 blocks
    k_gemm<128, 64, HS, HS, true><<<dim3(FFN / 64, MAXT128), 256, 0, stream>>>(
        xbf, w1T, Hb, rowtok, te128, tr128, FFN);
    // GEMM2 -> bf16 partials: 64x64 tiles, split-K=2, grid 8 x 72 x 2 = 1152 blocks
    k_gemm<64, 64, FFN, FFN / 2, false><<<dim3(HS / 64, MAXT64, 2), 256, 0, stream>>>(
        Hb, w2T, outv, rowtok, te64, tr64, HS);
    // combine split-K partials into y and buffer (writes ALL buffer slots)
    k_combine<<<NTOK * HS / 8 / 256, 256, 0, stream>>>(
        outv, ei, ew, hrof, y, buf);
}